// Round 7
// baseline (43.047 us; speedup 1.0000x reference)
//
#include <hip/hip_runtime.h>

#define KL   19
#define K2   361
#define W    256
#define H    256
#define HW   65536
#define C    3
#define PADL 9
#define B    2
#define TC   34            // tile cols: 16 pixels + 18 halo
#define TR   20            // tile rows: 2 pixel rows + 18 halo
#define TPOS (TR * TC)     // 680 spatial positions

// Sum across each 16-lane DPP row via v_add_f32 row_shr:{1,2,4,8}.
// Lane 15 of each row holds the full 16-lane sum.
__device__ __forceinline__ float dpp_sum16(float x) {
    int t;
    t = __builtin_amdgcn_update_dpp(0, __float_as_int(x), 0x111, 0xF, 0xF, true); // row_shr:1
    x += __int_as_float(t);
    t = __builtin_amdgcn_update_dpp(0, __float_as_int(x), 0x112, 0xF, 0xF, true); // row_shr:2
    x += __int_as_float(t);
    t = __builtin_amdgcn_update_dpp(0, __float_as_int(x), 0x114, 0xF, 0xF, true); // row_shr:4
    x += __int_as_float(t);
    t = __builtin_amdgcn_update_dpp(0, __float_as_int(x), 0x118, 0xF, 0xF, true); // row_shr:8
    x += __int_as_float(t);
    return x;
}

// One block = 16 cols x 2 rows = 32 output pixels (4096 blocks). Both rows'
// weight bursts (46 independent coalesced dword loads, ~11.8 KB/wave) are
// issued BEFORE any compute, so each wave keeps memory requests outstanding
// through both compute phases instead of going idle after a 23-load burst
// (the R6 residue). launch_bounds (256,6) raises the VGPR cap to 85 so the
// two w[23] arrays fit without R4-style spills; 24 waves/CU is still ample
// TLP. DPP (VALU) reduction; LDS tap reads are 16B-aligned b96, ~free.
__global__ __launch_bounds__(256, 6) void blur_fused(
    const float* __restrict__ in,     // (B, C, 256, 256)
    const float* __restrict__ kern,   // (B, HW, 19, 19)
    float* __restrict__ out)          // (B, C, 256, 256)
{
    __shared__ float tile[TPOS * 4];  // 10880 B

    const int tid = threadIdx.x;
    const int bid = blockIdx.x;
    const int b   = bid >> 11;             // 2048 blocks per batch
    const int rem = bid & 2047;
    const int i0  = (rem >> 4) << 1;       // row-pair base (0,2,...,254)
    const int j0  = (rem & 15) << 4;       // col base (multiple of 16)

    // ---- stage 20x34x3 window, plane-major (coalesced 256B per inst) ----
    const float* in_b = in + (size_t)b * (C * HW);
    #pragma unroll
    for (int k = 0; k < 8; ++k) {
        const int s = tid + 256 * k;       // 0..2047
        if (s < TPOS * 3) {                // 2040 useful slots
            const int ch  = s / TPOS;      // plane index 0..2 (magic-mul)
            const int pos = s - ch * TPOS;
            const int rr  = pos / TC;
            const int cc  = pos - rr * TC;
            int ro = i0 + rr - PADL;                   // [-9, 264]
            ro = (ro < 0) ? -ro : ro;
            ro = (ro > H - 1) ? 2 * (H - 1) - ro : ro;
            int co = j0 + cc - PADL;
            co = (co < 0) ? -co : co;
            co = (co > W - 1) ? 2 * (W - 1) - co : co;
            tile[4 * pos + ch] = in_b[ch * HW + ro * W + co];
        }
    }

    const int sub = tid & 15;              // lane within pixel group
    const int q   = tid >> 4;              // pixel column within block
    const float scale = 1.0f / (float)K2;

    const int ij0 = (i0 << 8) + j0 + q;                  // row 0 pixel
    const float* krow0 = kern + ((size_t)b * HW + ij0) * K2 + sub;
    const float* krow1 = krow0 + (size_t)W * K2;         // row 1 pixel

    // ---- both rows' weight bursts up front: 46 loads in flight ----
    float w0[23], w1[23];
    #pragma unroll
    for (int c = 0; c < 23; ++c) {
        const int t = sub + 16 * c;
        w0[c] = (t < K2) ? krow0[16 * c] : 0.f;          // guard only c==22
    }
    #pragma unroll
    for (int c = 0; c < 23; ++c) {
        const int t = sub + 16 * c;
        w1[c] = (t < K2) ? krow1[16 * c] : 0.f;
    }

    __syncthreads();                       // tile ready (placed after bursts)

    // ---- row 0 ----
    {
        float a0 = 0.f, a1 = 0.f, a2 = 0.f;
        #pragma unroll
        for (int c = 0; c < 23; ++c) {
            int t = sub + 16 * c;
            if (t > K2 - 1) t = K2 - 1;                  // clamp (w==0 there)
            const int ki = t / KL;
            const int kj = t - ki * KL;
            const float* src = &tile[(ki * TC + kj + q) * 4];
            a0 += w0[c] * src[0];
            a1 += w0[c] * src[1];
            a2 += w0[c] * src[2];
        }
        a0 = dpp_sum16(a0);
        a1 = dpp_sum16(a1);
        a2 = dpp_sum16(a2);
        if (sub == 15) {
            float* ob = out + (size_t)b * (C * HW) + ij0;
            ob[0]      = a0 * scale;
            ob[HW]     = a1 * scale;
            ob[2 * HW] = a2 * scale;
        }
    }

    // ---- row 1 (tile offset by one row = +TC positions) ----
    {
        float a0 = 0.f, a1 = 0.f, a2 = 0.f;
        #pragma unroll
        for (int c = 0; c < 23; ++c) {
            int t = sub + 16 * c;
            if (t > K2 - 1) t = K2 - 1;
            const int ki = t / KL;
            const int kj = t - ki * KL;
            const float* src = &tile[((ki + 1) * TC + kj + q) * 4];
            a0 += w1[c] * src[0];
            a1 += w1[c] * src[1];
            a2 += w1[c] * src[2];
        }
        a0 = dpp_sum16(a0);
        a1 = dpp_sum16(a1);
        a2 = dpp_sum16(a2);
        if (sub == 15) {
            float* ob = out + (size_t)b * (C * HW) + ij0 + W;
            ob[0]      = a0 * scale;
            ob[HW]     = a1 * scale;
            ob[2 * HW] = a2 * scale;
        }
    }
}

extern "C" void kernel_launch(void* const* d_in, const int* in_sizes, int n_in,
                              void* d_out, int out_size, void* d_ws, size_t ws_size,
                              hipStream_t stream) {
    const float* in   = (const float*)d_in[0];
    const float* kern = (const float*)d_in[1];
    float* out        = (float*)d_out;

    dim3 grid(B * (H / 2) * (W / 16)), block(256);   // 4096 blocks, 32 px each
    hipLaunchKernelGGL(blur_fused, grid, block, 0, stream, in, kern, out);
}